// Round 6
// baseline (328.616 us; speedup 1.0000x reference)
//
#include <hip/hip_runtime.h>
#include <hip/hip_bf16.h>

// Problem constants
#define N_NODES 4096
#define BATCH   128
#define DD      32           // D_IN == D_OUT

typedef float  f32x4  __attribute__((ext_vector_type(4)));
typedef __bf16 bf16x8 __attribute__((ext_vector_type(8)));
typedef int    i32x4  __attribute__((ext_vector_type(4)));
typedef int    i32x8  __attribute__((ext_vector_type(8)));

#define PREP_BLOCKS 2048
#define TR_BLOCKS   4096   // 64x64 tiles

// async global->LDS, 16 B per lane. LDS dest must be linear in lane (uniform base + lane*16).
__device__ __forceinline__ void async_copy16(const void* g, void* l) {
    __builtin_amdgcn_global_load_lds(
        (const __attribute__((address_space(1))) unsigned int*)g,
        (__attribute__((address_space(3))) unsigned int*)l,
        16, 0, 0);
}

// pack 4 floats -> 4 fp8 e4m3 bytes (OCP), one dword
__device__ __forceinline__ unsigned pack_fp8x4(float a, float b, float c, float d) {
    int v = __builtin_amdgcn_cvt_pk_fp8_f32(a, b, 0, false);   // bytes 0,1
    v     = __builtin_amdgcn_cvt_pk_fp8_f32(c, d, v, true);    // bytes 2,3
    return (unsigned)v;
}

// ---------------------------------------------------------------------------
// Pre-stage (unchanged, known-good):
// Blocks [0, PREP_BLOCKS): T8[m=(b*32+q)][i] = fp8( x @ Wn )
// Blocks [PREP_BLOCKS, +TR_BLOCKS): adjT8[j][i] = fp8( adj[i][j] * 4096 )
//   (2^12 scale removed exactly by the GEMM's B e8m0 scale byte 0x73)
// ---------------------------------------------------------------------------
__global__ __launch_bounds__(256) void k_pre(
    const float* __restrict__ x, const float* __restrict__ adj,
    const float* __restrict__ Wn,
    unsigned char* __restrict__ T8, unsigned char* __restrict__ adjT8)
{
    __shared__ float ts[64][65];
    const int tid = threadIdx.x;

    if (blockIdx.x < PREP_BLOCKS) {
        // ---- prep branch (MFMA, no LDS) ----
        const int lane = tid & 63;
        const int gw   = (blockIdx.x * 256 + tid) >> 6;  // wave id 0..8191
        const int m    = lane & 15;   // A row / C col index
        const int quad = lane >> 4;   // k-quad

        bf16x8 bn[2];
#pragma unroll
        for (int h = 0; h < 2; ++h) {
            const int n = m + h * 16;
#pragma unroll
            for (int j = 0; j < 8; ++j) {
                const int k = quad * 8 + j;
                bn[h][j] = (__bf16)Wn[k * 32 + n];
            }
        }

        for (int t = gw; t < 32768; t += 8192) {       // 16-row tiles, 4 iters/wave
            const int row0 = t << 4;                   // global row = b*4096 + i0
            const int b    = row0 >> 12;
            const int i0   = row0 & 4095;

            const float4* xp = (const float4*)(x + (size_t)(row0 + m) * DD + quad * 8);
            const float4 x0 = xp[0], x1 = xp[1];
            bf16x8 a;
            a[0] = (__bf16)x0.x; a[1] = (__bf16)x0.y; a[2] = (__bf16)x0.z; a[3] = (__bf16)x0.w;
            a[4] = (__bf16)x1.x; a[5] = (__bf16)x1.y; a[6] = (__bf16)x1.z; a[7] = (__bf16)x1.w;

            const f32x4 z = {};
            const f32x4 cT0 = __builtin_amdgcn_mfma_f32_16x16x32_bf16(a, bn[0], z, 0, 0, 0);
            const f32x4 cT1 = __builtin_amdgcn_mfma_f32_16x16x32_bf16(a, bn[1], z, 0, 0, 0);

            // C/D: col=lane&15, row=quad*4+reg (i-local, 4 consecutive)
            *(unsigned*)&T8[((size_t)(b * 32 + m))      * N_NODES + i0 + quad * 4] =
                pack_fp8x4(cT0[0], cT0[1], cT0[2], cT0[3]);
            *(unsigned*)&T8[((size_t)(b * 32 + m + 16)) * N_NODES + i0 + quad * 4] =
                pack_fp8x4(cT1[0], cT1[1], cT1[2], cT1[3]);
        }
    } else {
        // ---- transpose branch ----
        const int bid = blockIdx.x - PREP_BLOCKS;
        const int cx  = tid & 63;
        const int cy  = tid >> 6;
        const int i0  = (bid >> 6) << 6;
        const int j0  = (bid & 63) << 6;
#pragma unroll
        for (int r = 0; r < 16; ++r) {
            const int row = cy * 16 + r;
            ts[row][cx] = adj[(size_t)(i0 + row) * N_NODES + j0 + cx];
        }
        __syncthreads();
        const int il = (tid & 7) * 8;
        const int jb = tid >> 3;          // 0..31
#pragma unroll
        for (int rr = 0; rr < 2; ++rr) {
            const int jl = jb + rr * 32;
            float v[8];
#pragma unroll
            for (int k = 0; k < 8; ++k) v[k] = ts[il + k][jl] * 4096.0f;
            uint2 p;
            p.x = pack_fp8x4(v[0], v[1], v[2], v[3]);
            p.y = pack_fp8x4(v[4], v[5], v[6], v[7]);
            *(uint2*)&adjT8[(size_t)(j0 + jl) * N_NODES + i0 + il] = p;
        }
    }
}

// ---------------------------------------------------------------------------
// GEMM v6: round-2 structure (128x128 tile, 4 waves, 2-barrier loop, proven
// 97 us) with A REMOVED FROM LDS. Evidence: v1/v4b/v5 all pin at ~1800
// cyc/CU per 128^2-K-tile unit with MfmaUtil*dur == const 28 us -> LDS-read
// service is the binding resource, and schedule changes can't move it.
// A-fragments are per-wave-private, k-contiguous in T8, L1/L2-resident
// (2 MB/XCD) -> load straight to VGPRs (same af[] registers as before, new
// source), halving LDS reads (64 -> 32 per unit) and removing A's LDS
// writes. B keeps the proven global_load_lds + XOR-swizzle path. VGPR stays
// ~112 -> 4 blocks/CU co-residency covers the remaining B-drain (v1's
// proven overlap mechanism).
//           out[b*131072 + j*32 + q] = relu(U + C),  m = b*32+q
// U (self part) fused in epilogue from x, bit-identical to v3.
// ---------------------------------------------------------------------------
__global__ __launch_bounds__(256) void k_gemm_neigh(
    const unsigned char* __restrict__ A8,   // T8    [4096][4096] fp8
    const unsigned char* __restrict__ B8,   // adjT8 [4096][4096] fp8 (x4096)
    const float* __restrict__ x,            // [128][4096][32] f32
    const float* __restrict__ Ws,           // [32][32] f32
    float* __restrict__ out)                // [128][4096][32] pure store
{
    __shared__ alignas(16) unsigned char Bs[128 * 128];   // 16 KB (B only)

    const int tid   = threadIdx.x;
    const int lane  = tid & 63;
    const int wave  = tid >> 6;
    const int bm    = blockIdx.y << 7;
    const int bn    = blockIdx.x << 7;
    const int waveM = (wave >> 1) << 6;
    const int waveN = (wave & 1) << 6;
    const int lr    = lane & 15;   // row (A) / col (B) within 16-tile
    const int lq    = lane >> 4;   // k-chunk (32 bytes)
    const int sw    = lr & 7;      // read-side XOR swizzle (B only)

    f32x4 acc[4][4] = {};

    // B staging: row r = tid>>3 (+n*32); source chunk swizzled by r&7 so the
    // LDS image at (r, c16) holds global chunk c16 ^ (r&7)
    const int srow = tid >> 3;
    const int scol = ((tid & 7) ^ (srow & 7)) * 16;
    const unsigned char* gb = B8 + (size_t)(bn + srow) * 4096 + scol;
    char* lb = (char*)Bs + tid * 16;

    // A direct-from-global row bases: frag t -> row bm + waveM + t*16 + lr,
    // 32 k-contiguous bytes at k0 + lq*32 (identical bytes the LDS path
    // delivered: image chunk (2lq)^sw read at c=(2lq)^sw -> global 2lq).
    const unsigned char* arow[4];
#pragma unroll
    for (int t = 0; t < 4; ++t)
        arow[t] = A8 + (size_t)(bm + waveM + t * 16 + lr) * 4096 + lq * 32;

    for (int k0 = 0; k0 < 4096; k0 += 128) {
        // A loads first (L2-hit latency overlaps B's L3 staging latency)
        i32x8 af[4];
#pragma unroll
        for (int t = 0; t < 4; ++t) {
            const i32x4 alo = *(const i32x4*)(arow[t] + k0);
            const i32x4 ahi = *(const i32x4*)(arow[t] + k0 + 16);
            af[t][0]=alo[0]; af[t][1]=alo[1]; af[t][2]=alo[2]; af[t][3]=alo[3];
            af[t][4]=ahi[0]; af[t][5]=ahi[1]; af[t][6]=ahi[2]; af[t][7]=ahi[3];
        }
#pragma unroll
        for (int n = 0; n < 4; ++n)
            async_copy16(gb + (size_t)(n * 32) * 4096 + k0, lb + n * 4096);
        __syncthreads();   // drains vmcnt -> Bs complete (A regs waited at use)

        i32x8 bfr[4];
#pragma unroll
        for (int t = 0; t < 4; ++t) {
            const int rb = (waveN + t * 16 + lr) * 128;
            const int c0 = ((2 * lq)     ^ sw) * 16;
            const int c1 = ((2 * lq + 1) ^ sw) * 16;
            const i32x4 blo = *(const i32x4*)&Bs[rb + c0];
            const i32x4 bhi = *(const i32x4*)&Bs[rb + c1];
            bfr[t][0]=blo[0]; bfr[t][1]=blo[1]; bfr[t][2]=blo[2]; bfr[t][3]=blo[3];
            bfr[t][4]=bhi[0]; bfr[t][5]=bhi[1]; bfr[t][6]=bhi[2]; bfr[t][7]=bhi[3];
        }
#pragma unroll
        for (int tm = 0; tm < 4; ++tm)
#pragma unroll
            for (int tn = 0; tn < 4; ++tn)
                acc[tm][tn] = __builtin_amdgcn_mfma_scale_f32_16x16x128_f8f6f4(
                    af[tm], bfr[tn], acc[tm][tn],
                    0, 0,              // cbsz=fp8(e4m3), blgp=fp8(e4m3)
                    0, 0x7F,           // A scale: 2^0
                    0, 0x73);          // B scale: 2^-12 (undo adj*4096)
        __syncthreads();
    }

    // ---- epilogue: U = bf16(x) @ bf16(Ws), computed in the SAME fragment
    // layout as acc (row=q=lq*4+reg, col=j=lr), then relu(acc+U) pure store.
    const f32x4 z = {};

    // Ws^T A-fragments: A[m=q][k=p] = Ws[p*32+q], q = lr + h*16, p = lq*8+j
    bf16x8 ws[2];
#pragma unroll
    for (int h = 0; h < 2; ++h)
#pragma unroll
        for (int j = 0; j < 8; ++j)
            ws[h][j] = (__bf16)Ws[(lq * 8 + j) * 32 + lr + h * 16];

    const int b0 = (bm + waveM) >> 5;    // wave's m-range = 64 rows = 2 batches
#pragma unroll
    for (int bb = 0; bb < 2; ++bb) {
        const int b = b0 + bb;
        // x B-fragments for this batch: B[n=j][k=p], n = lr, one per tn
        bf16x8 xa[4];
#pragma unroll
        for (int tn = 0; tn < 4; ++tn) {
            const int gj = bn + waveN + tn * 16 + lr;
            const float4* xp = (const float4*)(x + ((size_t)b * N_NODES + gj) * DD + lq * 8);
            const float4 x0 = xp[0], x1 = xp[1];
            xa[tn][0] = (__bf16)x0.x; xa[tn][1] = (__bf16)x0.y;
            xa[tn][2] = (__bf16)x0.z; xa[tn][3] = (__bf16)x0.w;
            xa[tn][4] = (__bf16)x1.x; xa[tn][5] = (__bf16)x1.y;
            xa[tn][6] = (__bf16)x1.z; xa[tn][7] = (__bf16)x1.w;
        }
#pragma unroll
        for (int hh = 0; hh < 2; ++hh) {
            const int tm = bb * 2 + hh;          // acc tile for (b, q-half hh)
            const int q0 = hh * 16 + lq * 4;     // q of acc reg 0
#pragma unroll
            for (int tn = 0; tn < 4; ++tn) {
                const f32x4 u = __builtin_amdgcn_mfma_f32_16x16x32_bf16(
                    ws[hh], xa[tn], z, 0, 0, 0);
                const int gj = bn + waveN + tn * 16 + lr;
                float* p = out + (size_t)b * (N_NODES * DD) + (size_t)gj * DD + q0;
                float4 v;
                v.x = fmaxf(acc[tm][tn][0] + u[0], 0.0f);
                v.y = fmaxf(acc[tm][tn][1] + u[1], 0.0f);
                v.z = fmaxf(acc[tm][tn][2] + u[2], 0.0f);
                v.w = fmaxf(acc[tm][tn][3] + u[3], 0.0f);
                *(float4*)p = v;
            }
        }
    }
}

extern "C" void kernel_launch(void* const* d_in, const int* in_sizes, int n_in,
                              void* d_out, int out_size, void* d_ws, size_t ws_size,
                              hipStream_t stream) {
    const float* x   = (const float*)d_in[0];  // [128, 4096*32]
    const float* adj = (const float*)d_in[1];  // [4096, 4096]
    const float* Wn  = (const float*)d_in[2];  // [32, 32]
    const float* Ws  = (const float*)d_in[3];  // [32, 32]
    float* out = (float*)d_out;                // [128, 4096*32]

    // workspace: T8 fp8 (16 MB) | adjT8 fp8 (16 MB)
    unsigned char* T8    = (unsigned char*)d_ws;
    unsigned char* adjT8 = T8 + (size_t)N_NODES * N_NODES;

    hipLaunchKernelGGL(k_pre, dim3(PREP_BLOCKS + TR_BLOCKS), dim3(256), 0, stream,
                       x, adj, Wn, T8, adjT8);
    hipLaunchKernelGGL(k_gemm_neigh, dim3(32, 32), dim3(256), 0, stream,
                       T8, adjT8, x, Ws, out);
}